// Round 8
// baseline (378.588 us; speedup 1.0000x reference)
//
#include <hip/hip_runtime.h>
#include <hip/hip_bf16.h>

#define NBANDS 31
#define CDIM 128
#define TDIM 2000
#define HDIM 512
#define MTOT 8000
#define MAXO 204
#define OPAD 224       // b2 bias padded length
#define NGRP 124
#define NMB 125        // 64-row m-blocks per band
#define NWG (NBANDS * NMB)
#define NMTILE 504     // padded 16-row m-tiles per band
#define SMAX 13

typedef __attribute__((ext_vector_type(8))) short short8;
typedef __attribute__((ext_vector_type(4))) float f32x4;
typedef __attribute__((ext_vector_type(4))) unsigned int u32x4;
typedef __bf16 bf16x8 __attribute__((ext_vector_type(8)));

__constant__ int d_bw[NBANDS]   = {2,3,3,3,3,3,3,3,3,3,3,8,8,8,8,8,8,8,8,8,8,8,8,16,16,16,16,16,16,16,17};
__constant__ int d_boff[NBANDS] = {0,2,5,8,11,14,17,20,23,26,29,32,40,48,56,64,72,80,88,96,104,112,120,128,144,160,176,192,208,224,240};
__constant__ int d_nn16[NBANDS] = {2,3,3,3,3,3,3,3,3,3,3,6,6,6,6,6,6,6,6,6,6,6,6,12,12,12,12,12,12,12,13};

__device__ __forceinline__ unsigned short f2bf(float f) {
  unsigned int u = __float_as_uint(f);
  return (unsigned short)((u + 0x7fffu + ((u >> 16) & 1u)) >> 16);
}

// packed f32x2 -> bf16x2 (RNE); no builtin on gfx950 (T12)
__device__ __forceinline__ unsigned int cvt_pk_bf16(float lo, float hi) {
  unsigned int r;
  asm("v_cvt_pk_bf16_f32 %0, %1, %2" : "=v"(r) : "v"(lo), "v"(hi));
  return r;
}

// tanh(x) = 1 - 2/(exp2(2*log2e*x)+1)
__device__ __forceinline__ float fast_tanh(float x) {
  float p = __builtin_amdgcn_exp2f(2.885390082f * x);
  return 1.0f - 2.0f * __builtin_amdgcn_rcpf(p + 1.0f);
}

__device__ __forceinline__ float fast_sigmoid(float x) {
  return __builtin_amdgcn_rcpf(1.0f + __builtin_amdgcn_exp2f(-1.442695041f * x));
}

__device__ __forceinline__ f32x4 mfma_bf16(short8 a, short8 b, f32x4 c) {
  return __builtin_amdgcn_mfma_f32_16x16x32_bf16(
      __builtin_bit_cast(bf16x8, a), __builtin_bit_cast(bf16x8, b), c, 0, 0, 0);
}

// ------------- finalize group stats -------------
__global__ void k_finalize(const float* __restrict__ wsum, const float* __restrict__ wsq,
                           float* __restrict__ gmean, float* __restrict__ grstd) {
  int g = threadIdx.x;
  if (g < NGRP) {
    const float n = (float)(CDIM * TDIM);
    float m = wsum[g] / n;
    float v = wsq[g] / n - m * m;
    gmean[g] = m;
    grstd[g] = rsqrtf(v + 1e-5f);
  }
}

// ------------- prep fc1: fold norm affine, MFMA-A fragment order ------------
// w1f: [k][nc 4][hh 8][kk 4][lane 64][8e]; lane l = (h&15)|(q<<4) holds
//   W1fold[h][c = kk*32 + q*8 + j]
__global__ void k_prep_w1(const float* __restrict__ fc1_w, const float* __restrict__ norm_w,
                          const float* __restrict__ norm_b, const float* __restrict__ fc1_b,
                          unsigned short* __restrict__ w1f, float* __restrict__ t1,
                          float* __restrict__ t2) {
  int kn = blockIdx.x;              // k*512 + n(h)
  int k = kn >> 9, n = kn & 511;
  int c = threadIdx.x;              // 128 threads
  float w  = fc1_w[(size_t)kn * CDIM + c];
  float nw = norm_w[k * CDIM + c];
  float nb = norm_b[k * CDIM + c];
  float wp = w * nw;
  {
    int nc = n >> 7, hh = (n >> 4) & 7, kk = c >> 5;
    int lnw = (n & 15) | (((c >> 3) & 3) << 4);
    size_t eoff = ((((size_t)(k * 4 + nc) * 8 + hh) * 4 + kk) * 64 + lnw) * 8 + (c & 7);
    w1f[eoff] = f2bf(wp);
  }
  float s1 = wp, s2 = w * nb;
  #pragma unroll
  for (int off = 32; off >= 1; off >>= 1) {
    s1 += __shfl_down(s1, off);
    s2 += __shfl_down(s2, off);
  }
  __shared__ float r1[2], r2[2];
  if ((threadIdx.x & 63) == 0) { r1[threadIdx.x >> 6] = s1; r2[threadIdx.x >> 6] = s2; }
  __syncthreads();
  if (threadIdx.x == 0) {
    t1[kn] = r1[0] + r1[1];
    t2[kn] = r2[0] + r2[1] + fc1_b[kn];
  }
}

// ------------- prep fc2: GLU-pair permute + pi(k) column permute ------------
// w2f: [k][ks 16][ot 16][lane 64][8e].  Within each 32-h k-step the column
// order is pi(k) = ((k>>2)&1)*16 + (k>>3)*4 + (k&3), matching fc1's C-frag
// consumed directly as fc2's B-frag (zero-shuffle fc1->fc2 handoff).
__global__ void k_prep_w2(const float* __restrict__ fc2_w, const float* __restrict__ fc2_b,
                          unsigned short* __restrict__ w2f, float* __restrict__ b2) {
  int ko = blockIdx.x;              // k*256 + o
  int k = ko >> 8;
  int o = ko & 255;
  int bw = d_bw[k];
  int O2 = 12 * bw, hf = 6 * bw;
  bool valid = o < O2;
  int srcrow = valid ? ((o & 1) ? (hf + (o >> 1)) : (o >> 1)) : 0;
  const float* sp = fc2_w + ((size_t)k * MAXO + srcrow) * HDIM;
  if (threadIdx.x == 0 && o < OPAD)
    b2[k * OPAD + o] = valid ? fc2_b[k * MAXO + srcrow] : 0.f;
  int ot = o >> 4, rr = o & 15;
  for (int j = threadIdx.x; j < HDIM; j += 256) {
    int ks = j >> 5, hp = j & 31;
    int q  = (hp >> 2) & 3;                 // inverse of pi: lane quad
    int jj = ((hp >> 4) << 2) | (hp & 3);   // elem = ht*4 + r
    unsigned short val = valid ? f2bf(sp[j]) : (unsigned short)0;
    size_t eoff = (((size_t)(k * 16 + ks)) * 16 + ot) * 512 + (size_t)(rr | (q << 4)) * 8 + jj;
    w2f[eoff] = val;
  }
}

// ------------- transpose x[B,C,T,K] -> xtf fragment order, fused stats ------
__global__ void k_transpose(const float* __restrict__ x, unsigned short* __restrict__ xtf,
                            float* __restrict__ wsum, float* __restrict__ wsq) {
  __shared__ unsigned short tile[248 * 128];   // rows staggered by 4f bytes
  __shared__ float sred[256], sqred[256];
  const int t0 = blockIdx.x * 8;
  const int b = blockIdx.y;
  const int tid = threadIdx.x;
  const float* p = x + ((size_t)b * CDIM * TDIM + t0) * NBANDS;
  float s = 0.f, sq = 0.f;
  if (tid < 248) {
    const int f = tid;
    char* row = (char*)tile + f * 256;
    const int st = 4 * f;
    #pragma unroll 4
    for (int c2 = 0; c2 < 64; ++c2) {
      float v0 = p[(size_t)c2 * 124000 + f];
      float v1 = p[(size_t)c2 * 124000 + 62000 + f];
      s += v0 + v1;
      sq += v0 * v0 + v1 * v1;
      *(unsigned int*)(row + ((4 * c2 + st) & 255)) = cvt_pk_bf16(v0, v1);
    }
  }
  sred[tid] = s; sqred[tid] = sq;
  __syncthreads();
  if (tid < 31) {
    float ss = 0.f, qs = 0.f;
    #pragma unroll
    for (int j = 0; j < 8; ++j) { ss += sred[tid + 31 * j]; qs += sqred[tid + 31 * j]; }
    atomicAdd(&wsum[b * 31 + tid], ss);
    atomicAdd(&wsq [b * 31 + tid], qs);
  }
  for (int idx = tid; idx < 3968; idx += 256) {
    int ti = idx & 7, q4w = (idx >> 3) & 3, kkw = (idx >> 5) & 3, kb = idx >> 7;
    int f = ti * 31 + kb;
    const char* row = (const char*)tile + f * 256;
    const int st = 4 * f;
    u32x4 v;
    #pragma unroll
    for (int j = 0; j < 4; ++j)
      v[j] = *(const unsigned int*)(row + ((kkw * 64 + q4w * 16 + 4 * j + st) & 255));
    int m = b * TDIM + t0 + ti;
    int mtile = m >> 4, mrow = m & 15;
    size_t eoff = ((((size_t)kb * NMTILE + mtile) * 4 + kkw) * 64 + (mrow | (q4w << 4))) * 8;
    *(u32x4*)(xtf + eoff) = v;
  }
}

// ------------- fused GEMM: barrier-free, wave-independent, 16 m/wave --------
// Each wave owns 16 m-rows end-to-end; fc1 C-frag consumed directly as fc2
// B-frag via pi(k) permute in w2f.  One uniform kernel for all bands.
// (256,4) => VGPR cap 2048/16 = 128; live state ~110 regs (no spill; WRITE_SIZE
// blowup would be the spill tripwire per R4).
__launch_bounds__(256, 4)
__global__ void k_gemm(const unsigned short* __restrict__ xtf,
                       const unsigned short* __restrict__ w1f,
                       const float* __restrict__ t1p, const float* __restrict__ t2p,
                       const unsigned short* __restrict__ w2f,
                       const float* __restrict__ b2p,
                       const float* __restrict__ gmean, const float* __restrict__ grstd,
                       float* __restrict__ out) {
  extern __shared__ float Ls[];

  // bijective XCD-aware swizzle (nwg = 3875 = 8*484 + 3)
  const int bid = blockIdx.x;
  const int qq = NWG >> 3, r8 = NWG & 7;
  const int xcd = bid & 7, ixd = bid >> 3;
  const int wg = (xcd < r8 ? xcd * (qq + 1) : r8 * (qq + 1) + (xcd - r8) * qq) + ixd;
  const int k = wg / NMB;
  const int mb = wg - k * NMB;
  const int m0 = mb * 64;

  const int tid = threadIdx.x;
  const int lane = tid & 63;
  const int wid = tid >> 6;          // 4 waves, 16 m-rows each
  const int col = lane & 15;
  const int q4 = lane >> 4;

  const int bw = d_bw[k];
  const int nn = d_nn16[k];          // <= SMAX
  const int half = 6 * bw;
  const int boffk = d_boff[k];

  // X fragments in registers for the whole kernel (16 VGPR)
  const int mt = (m0 >> 4) + wid;
  short8 xv[4];
  #pragma unroll
  for (int kk = 0; kk < 4; ++kk)
    xv[kk] = *(const short8*)(xtf + (((size_t)k * NMTILE + mt) * 4 + kk) * 512 + lane * 8);

  // norm constants (acc col = m = lane&15)
  float rs1, rm1;
  {
    int mr = m0 + wid * 16 + col;
    int mc = mr < (MTOT - 1) ? mr : (MTOT - 1);
    int g = (mc / 2000) * NBANDS + k;
    rs1 = grstd[g];
    rm1 = rs1 * gmean[g];
  }

  const f32x4 fz = {0.f, 0.f, 0.f, 0.f};
  f32x4 acc2[SMAX];
  #pragma unroll
  for (int s = 0; s < SMAX; ++s) acc2[s] = fz;

  const float* t1k = t1p + k * HDIM + q4 * 4;
  const float* t2k = t2p + k * HDIM + q4 * 4;

  #pragma unroll 2
  for (int c = 0; c < 16; ++c) {     // 16 chunks of 32 h
    const unsigned short* w1b =
        w1f + ((size_t)(k * 4 + (c >> 2)) * 8 + (size_t)(c & 3) * 2) * 2048 + lane * 8;
    f32x4 a1[2];
    a1[0] = fz; a1[1] = fz;
    #pragma unroll
    for (int kk = 0; kk < 4; ++kk) {
      short8 wa0 = *(const short8*)(w1b + kk * 512);
      short8 wa1 = *(const short8*)(w1b + 2048 + kk * 512);
      a1[0] = mfma_bf16(wa0, xv[kk], a1[0]);
      a1[1] = mfma_bf16(wa1, xv[kk], a1[1]);
    }
    // tanh epilogue -> B-frag in-lane (pi(k) order), zero shuffles
    u32x4 hbw;
    #pragma unroll
    for (int ht = 0; ht < 2; ++ht) {
      const f32x4 c1 = *(const f32x4*)(t1k + c * 32 + ht * 16);
      const f32x4 c2 = *(const f32x4*)(t2k + c * 32 + ht * 16);
      f32x4 v = a1[ht];
      float e0 = fast_tanh(fmaf(rs1, v[0], fmaf(-rm1, c1[0], c2[0])));
      float e1 = fast_tanh(fmaf(rs1, v[1], fmaf(-rm1, c1[1], c2[1])));
      float e2 = fast_tanh(fmaf(rs1, v[2], fmaf(-rm1, c1[2], c2[2])));
      float e3 = fast_tanh(fmaf(rs1, v[3], fmaf(-rm1, c1[3], c2[3])));
      hbw[ht * 2]     = cvt_pk_bf16(e0, e1);
      hbw[ht * 2 + 1] = cvt_pk_bf16(e2, e3);
    }
    const short8 hb = __builtin_bit_cast(short8, hbw);
    // fc2 partial over this 32-h chunk
    const unsigned short* w2b = w2f + ((size_t)(k * 16 + c) * 16) * 512 + lane * 8;
    #pragma unroll
    for (int s = 0; s < SMAX; ++s) {
      if (s < nn) {                  // wave-uniform branch (nn in SGPR)
        short8 wb = *(const short8*)(w2b + s * 512);
        acc2[s] = mfma_bf16(wb, hb, acc2[s]);
      }
    }
  }

  // ---- GLU epilogue: pairs (a,g) are adjacent regs in-lane ----
  const float* b2k = b2p + (size_t)k * OPAD;
  const bool plain = (m0 / 2000 == (m0 + 63) / 2000) && (m0 + 64 <= MTOT);
  if (plain) {
    #pragma unroll
    for (int s = 0; s < SMAX; ++s) {
      if (s < nn) {
        f32x4 bias = *(const f32x4*)(b2k + s * 16 + q4 * 4);
        const int tloc = wid * 16 + col;
        f32x4 v = acc2[s];
        #pragma unroll
        for (int p = 0; p < 2; ++p) {
          float a = v[2 * p] + bias[2 * p];
          float g = v[2 * p + 1] + bias[2 * p + 1];
          int op = s * 8 + q4 * 2 + p;
          if (op < half) {
            int orr = op / 6, occ = op - orr * 6;
            Ls[(orr * 64 + tloc) * 6 + occ] = a * fast_sigmoid(g);
          }
        }
      }
    }
    __syncthreads();
    const int bb = m0 / 2000;
    const int tb = m0 - bb * 2000;
    const size_t obase = ((size_t)bb * 257 + boffk) * 2000;
    const int tot = bw * 192;          // u64 chunks (64 tok * 6 f32 / 2 per row)
    for (int ii = tid; ii < tot; ii += 256) {
      int orr = ii / 192;
      int rem = ii - orr * 192;
      *(unsigned long long*)(out + (obase + (size_t)orr * 2000 + tb) * 6 + rem * 2) =
          *(const unsigned long long*)(Ls + orr * 384 + rem * 2);
    }
  } else {
    // boundary/tail blocks: scatter store
    #pragma unroll
    for (int s = 0; s < SMAX; ++s) {
      if (s < nn) {
        f32x4 bias = *(const f32x4*)(b2k + s * 16 + q4 * 4);
        const int m = m0 + wid * 16 + col;
        f32x4 v = acc2[s];
        #pragma unroll
        for (int p = 0; p < 2; ++p) {
          float a = v[2 * p] + bias[2 * p];
          float g = v[2 * p + 1] + bias[2 * p + 1];
          int op = s * 8 + q4 * 2 + p;
          if (op < half && m < MTOT) {
            int bbm = m / 2000;
            int t = m - bbm * 2000;
            int orr = op / 6, occ = op - orr * 6;
            out[(((size_t)bbm * 257 + boffk + orr) * TDIM + t) * 6 + occ] =
                a * fast_sigmoid(g);
          }
        }
      }
    }
  }
}

extern "C" void kernel_launch(void* const* d_in, const int* in_sizes, int n_in,
                              void* d_out, int out_size, void* d_ws, size_t ws_size,
                              hipStream_t stream) {
  const float* x      = (const float*)d_in[0];
  const float* norm_w = (const float*)d_in[1];
  const float* norm_b = (const float*)d_in[2];
  const float* fc1_w  = (const float*)d_in[3];
  const float* fc1_b  = (const float*)d_in[4];
  const float* fc2_w  = (const float*)d_in[5];
  const float* fc2_b  = (const float*)d_in[6];
  float* out = (float*)d_out;
  char* ws = (char*)d_ws;

  float* wsum  = (float*)(ws);
  float* wsq   = (float*)(ws + 512);
  float* gmean = (float*)(ws + 1024);
  float* grstd = (float*)(ws + 1536);
  size_t off = 4096;
  unsigned short* xtf = (unsigned short*)(ws + off); off += (size_t)NBANDS * NMTILE * 4 * 512 * 2;
  unsigned short* w1f = (unsigned short*)(ws + off); off += (size_t)NBANDS * 4 * 8 * 4 * 512 * 2;
  float* t1p = (float*)(ws + off); off += (size_t)NBANDS * HDIM * 4;
  float* t2p = (float*)(ws + off); off += (size_t)NBANDS * HDIM * 4;
  unsigned short* w2f = (unsigned short*)(ws + off); off += (size_t)NBANDS * 16 * 16 * 512 * 2;
  float* b2p = (float*)(ws + off); off += (size_t)NBANDS * OPAD * 4;

  hipMemsetAsync(ws, 0, 1024, stream);
  hipLaunchKernelGGL(k_prep_w1, dim3(NBANDS * HDIM), dim3(128), 0, stream,
                     fc1_w, norm_w, norm_b, fc1_b, w1f, t1p, t2p);
  hipLaunchKernelGGL(k_prep_w2, dim3(NBANDS * 256), dim3(256), 0, stream,
                     fc2_w, fc2_b, w2f, b2p);
  hipLaunchKernelGGL(k_transpose, dim3(250, 4), dim3(256), 0, stream, x, xtf, wsum, wsq);
  hipLaunchKernelGGL(k_finalize, dim3(1), dim3(128), 0, stream, wsum, wsq, gmean, grstd);

  hipFuncSetAttribute((const void*)k_gemm, hipFuncAttributeMaxDynamicSharedMemorySize, 26112);
  hipLaunchKernelGGL(k_gemm, dim3(NWG), dim3(256), 26112, stream,
                     xtf, w1f, t1p, t2p, w2f, b2p, gmean, grstd, out);
}

// Round 9
// 288.427 us; speedup vs baseline: 1.3126x; 1.3126x over previous
//
#include <hip/hip_runtime.h>
#include <hip/hip_bf16.h>

#define NBANDS 31
#define CDIM 128
#define TDIM 2000
#define HDIM 512
#define MTOT 8000
#define MAXO 204
#define OPAD 224       // b2 bias padded length
#define NGRP 124
#define NMTILE 504     // padded 16-row m-tiles per band

typedef __attribute__((ext_vector_type(8))) short short8;
typedef __attribute__((ext_vector_type(4))) float f32x4;
typedef __attribute__((ext_vector_type(4))) unsigned int u32x4;
typedef __bf16 bf16x8 __attribute__((ext_vector_type(8)));

__constant__ int d_bw[NBANDS]   = {2,3,3,3,3,3,3,3,3,3,3,8,8,8,8,8,8,8,8,8,8,8,8,16,16,16,16,16,16,16,17};
__constant__ int d_boff[NBANDS] = {0,2,5,8,11,14,17,20,23,26,29,32,40,48,56,64,72,80,88,96,104,112,120,128,144,160,176,192,208,224,240};

__device__ __forceinline__ unsigned short f2bf(float f) {
  unsigned int u = __float_as_uint(f);
  return (unsigned short)((u + 0x7fffu + ((u >> 16) & 1u)) >> 16);
}

// packed f32x2 -> bf16x2 (RNE); no builtin on gfx950 (T12)
__device__ __forceinline__ unsigned int cvt_pk_bf16(float lo, float hi) {
  unsigned int r;
  asm("v_cvt_pk_bf16_f32 %0, %1, %2" : "=v"(r) : "v"(lo), "v"(hi));
  return r;
}

// tanh(x) = 1 - 2/(exp2(2*log2e*x)+1)
__device__ __forceinline__ float fast_tanh(float x) {
  float p = __builtin_amdgcn_exp2f(2.885390082f * x);
  return 1.0f - 2.0f * __builtin_amdgcn_rcpf(p + 1.0f);
}

__device__ __forceinline__ float fast_sigmoid(float x) {
  return __builtin_amdgcn_rcpf(1.0f + __builtin_amdgcn_exp2f(-1.442695041f * x));
}

__device__ __forceinline__ f32x4 mfma_bf16(short8 a, short8 b, f32x4 c) {
  return __builtin_amdgcn_mfma_f32_16x16x32_bf16(
      __builtin_bit_cast(bf16x8, a), __builtin_bit_cast(bf16x8, b), c, 0, 0, 0);
}

// ------------- finalize group stats -------------
__global__ void k_finalize(const float* __restrict__ wsum, const float* __restrict__ wsq,
                           float* __restrict__ gmean, float* __restrict__ grstd) {
  int g = threadIdx.x;
  if (g < NGRP) {
    const float n = (float)(CDIM * TDIM);
    float m = wsum[g] / n;
    float v = wsq[g] / n - m * m;
    gmean[g] = m;
    grstd[g] = rsqrtf(v + 1e-5f);
  }
}

// ------------- prep fc1: fold norm affine, MFMA-A fragment order ------------
// w1f: [k][nc 4][hh 8][kk 4][lane 64][8e]; lane l = (h&15)|(q<<4) holds
//   W1fold[h][c = kk*32 + q*8 + j]
__global__ void k_prep_w1(const float* __restrict__ fc1_w, const float* __restrict__ norm_w,
                          const float* __restrict__ norm_b, const float* __restrict__ fc1_b,
                          unsigned short* __restrict__ w1f, float* __restrict__ t1,
                          float* __restrict__ t2) {
  int kn = blockIdx.x;              // k*512 + n(h)
  int k = kn >> 9, n = kn & 511;
  int c = threadIdx.x;              // 128 threads
  float w  = fc1_w[(size_t)kn * CDIM + c];
  float nw = norm_w[k * CDIM + c];
  float nb = norm_b[k * CDIM + c];
  float wp = w * nw;
  {
    int nc = n >> 7, hh = (n >> 4) & 7, kk = c >> 5;
    int lnw = (n & 15) | (((c >> 3) & 3) << 4);
    size_t eoff = ((((size_t)(k * 4 + nc) * 8 + hh) * 4 + kk) * 64 + lnw) * 8 + (c & 7);
    w1f[eoff] = f2bf(wp);
  }
  float s1 = wp, s2 = w * nb;
  #pragma unroll
  for (int off = 32; off >= 1; off >>= 1) {
    s1 += __shfl_down(s1, off);
    s2 += __shfl_down(s2, off);
  }
  __shared__ float r1[2], r2[2];
  if ((threadIdx.x & 63) == 0) { r1[threadIdx.x >> 6] = s1; r2[threadIdx.x >> 6] = s2; }
  __syncthreads();
  if (threadIdx.x == 0) {
    t1[kn] = r1[0] + r1[1];
    t2[kn] = r2[0] + r2[1] + fc1_b[kn];
  }
}

// ------------- prep fc2: GLU-pair permute + pi(k) column permute ------------
// w2f: [k][ks 16][ot 16][lane 64][8e].  Within each 32-h k-step the column
// order is pi(k) = ((k>>2)&1)*16 + (k>>3)*4 + (k&3), matching fc1's C-frag
// consumed directly as fc2's B-frag.  Rows o >= 12*bw are ZERO (branch-free
// padded fc2 in k_gemm relies on this).
__global__ void k_prep_w2(const float* __restrict__ fc2_w, const float* __restrict__ fc2_b,
                          unsigned short* __restrict__ w2f, float* __restrict__ b2) {
  int ko = blockIdx.x;              // k*256 + o
  int k = ko >> 8;
  int o = ko & 255;
  int bw = d_bw[k];
  int O2 = 12 * bw, hf = 6 * bw;
  bool valid = o < O2;
  int srcrow = valid ? ((o & 1) ? (hf + (o >> 1)) : (o >> 1)) : 0;
  const float* sp = fc2_w + ((size_t)k * MAXO + srcrow) * HDIM;
  if (threadIdx.x == 0 && o < OPAD)
    b2[k * OPAD + o] = valid ? fc2_b[k * MAXO + srcrow] : 0.f;
  int ot = o >> 4, rr = o & 15;
  for (int j = threadIdx.x; j < HDIM; j += 256) {
    int ks = j >> 5, hp = j & 31;
    int q  = (hp >> 2) & 3;                 // inverse of pi: lane quad
    int jj = ((hp >> 4) << 2) | (hp & 3);   // elem = ht*4 + r
    unsigned short val = valid ? f2bf(sp[j]) : (unsigned short)0;
    size_t eoff = (((size_t)(k * 16 + ks)) * 16 + ot) * 512 + (size_t)(rr | (q << 4)) * 8 + jj;
    w2f[eoff] = val;
  }
}

// ------------- transpose x[B,C,T,K] -> xtf fragment order, fused stats ------
__global__ void k_transpose(const float* __restrict__ x, unsigned short* __restrict__ xtf,
                            float* __restrict__ wsum, float* __restrict__ wsq) {
  __shared__ unsigned short tile[248 * 128];   // rows staggered by 4f bytes
  __shared__ float sred[256], sqred[256];
  const int t0 = blockIdx.x * 8;
  const int b = blockIdx.y;
  const int tid = threadIdx.x;
  const float* p = x + ((size_t)b * CDIM * TDIM + t0) * NBANDS;
  float s = 0.f, sq = 0.f;
  if (tid < 248) {
    const int f = tid;
    char* row = (char*)tile + f * 256;
    const int st = 4 * f;
    #pragma unroll 4
    for (int c2 = 0; c2 < 64; ++c2) {
      float v0 = p[(size_t)c2 * 124000 + f];
      float v1 = p[(size_t)c2 * 124000 + 62000 + f];
      s += v0 + v1;
      sq += v0 * v0 + v1 * v1;
      *(unsigned int*)(row + ((4 * c2 + st) & 255)) = cvt_pk_bf16(v0, v1);
    }
  }
  sred[tid] = s; sqred[tid] = sq;
  __syncthreads();
  if (tid < 31) {
    float ss = 0.f, qs = 0.f;
    #pragma unroll
    for (int j = 0; j < 8; ++j) { ss += sred[tid + 31 * j]; qs += sqred[tid + 31 * j]; }
    atomicAdd(&wsum[b * 31 + tid], ss);
    atomicAdd(&wsq [b * 31 + tid], qs);
  }
  for (int idx = tid; idx < 3968; idx += 256) {
    int ti = idx & 7, q4w = (idx >> 3) & 3, kkw = (idx >> 5) & 3, kb = idx >> 7;
    int f = ti * 31 + kb;
    const char* row = (const char*)tile + f * 256;
    const int st = 4 * f;
    u32x4 v;
    #pragma unroll
    for (int j = 0; j < 4; ++j)
      v[j] = *(const unsigned int*)(row + ((kkw * 64 + q4w * 16 + 4 * j + st) & 255));
    int m = b * TDIM + t0 + ti;
    int mtile = m >> 4, mrow = m & 15;
    size_t eoff = ((((size_t)kb * NMTILE + mtile) * 4 + kkw) * 64 + (mrow | (q4w << 4))) * 8;
    *(u32x4*)(xtf + eoff) = v;
  }
}

// ------------- fused GEMM: barrier-free, branch-free main loop --------------
// Each wave owns MR*16 m-rows end-to-end; fc1 C-frag consumed directly as fc2
// B-frag via pi(k) permute baked into w2f.  fc2 tile count padded to the
// compile-time class SMAX (zero weights) => straight-line loads/MFMAs the
// compiler can pipeline (runtime-nn branches exposed ~300cy L2 latency per
// W2 load in R5-R8 => ~3% pipe utilization).  (256,2): no AGPR ping-pong
// (R8: (256,4) -> VGPR 52 + AGPR shuffling), no spill (R4).
template<int SMAX, int MR, int NMBK>
__launch_bounds__(256, 2)
__global__ void k_gemm(const unsigned short* __restrict__ xtf,
                       const unsigned short* __restrict__ w1f,
                       const float* __restrict__ t1p, const float* __restrict__ t2p,
                       const unsigned short* __restrict__ w2f,
                       const float* __restrict__ b2p,
                       const float* __restrict__ gmean, const float* __restrict__ grstd,
                       float* __restrict__ out, int kbase, int nwg) {
  extern __shared__ float Ls[];
  const int MW = MR * 16;            // m-rows per wave
  const int MB = MR * 64;            // m-rows per block

  // bijective XCD-aware swizzle
  const int bid = blockIdx.x;
  const int qq = nwg >> 3, r8 = nwg & 7;
  const int xcd = bid & 7, ixd = bid >> 3;
  const int wg = (xcd < r8 ? xcd * (qq + 1) : r8 * (qq + 1) + (xcd - r8) * qq) + ixd;
  const int kl = wg / NMBK;
  const int k = kbase + kl;
  const int mb = wg - kl * NMBK;
  const int m0 = mb * MB;

  const int tid = threadIdx.x;
  const int lane = tid & 63;
  const int wid = tid >> 6;          // 4 waves
  const int col = lane & 15;
  const int q4 = lane >> 4;

  const int bw = d_bw[k];
  const int half = 6 * bw;
  const int boffk = d_boff[k];

  // X fragments in registers for the whole kernel
  const int mt0 = (m0 >> 4) + wid * MR;
  short8 xv[MR][4];
  #pragma unroll
  for (int r = 0; r < MR; ++r)
    #pragma unroll
    for (int kk = 0; kk < 4; ++kk)
      xv[r][kk] = *(const short8*)(xtf +
          (((size_t)k * NMTILE + mt0 + r) * 4 + kk) * 512 + lane * 8);

  // norm constants (acc col = m = lane&15)
  float rs[MR], rm[MR];
  #pragma unroll
  for (int r = 0; r < MR; ++r) {
    int mr = m0 + wid * MW + r * 16 + col;
    int mc = mr < (MTOT - 1) ? mr : (MTOT - 1);
    int g = (mc / 2000) * NBANDS + k;
    rs[r] = grstd[g];
    rm[r] = rs[r] * gmean[g];
  }

  const f32x4 fz = {0.f, 0.f, 0.f, 0.f};
  f32x4 acc2[SMAX][MR];
  #pragma unroll
  for (int s = 0; s < SMAX; ++s)
    #pragma unroll
    for (int r = 0; r < MR; ++r) acc2[s][r] = fz;

  const float* t1k = t1p + k * HDIM + q4 * 4;
  const float* t2k = t2p + k * HDIM + q4 * 4;

  #pragma unroll 2
  for (int c = 0; c < 16; ++c) {     // 16 chunks of 32 h, straight-line body
    const unsigned short* w1b =
        w1f + ((size_t)(k * 4 + (c >> 2)) * 8 + (size_t)(c & 3) * 2) * 2048 + lane * 8;
    f32x4 a1[2][MR];
    #pragma unroll
    for (int r = 0; r < MR; ++r) { a1[0][r] = fz; a1[1][r] = fz; }
    #pragma unroll
    for (int kk = 0; kk < 4; ++kk) {
      short8 wa0 = *(const short8*)(w1b + kk * 512);
      short8 wa1 = *(const short8*)(w1b + 2048 + kk * 512);
      #pragma unroll
      for (int r = 0; r < MR; ++r) {
        a1[0][r] = mfma_bf16(wa0, xv[r][kk], a1[0][r]);
        a1[1][r] = mfma_bf16(wa1, xv[r][kk], a1[1][r]);
      }
    }
    // tanh epilogue -> B-frag in-lane (pi(k) order), zero shuffles
    short8 hb[MR];
    #pragma unroll
    for (int r = 0; r < MR; ++r) {
      u32x4 hbw;
      #pragma unroll
      for (int ht = 0; ht < 2; ++ht) {
        const f32x4 c1 = *(const f32x4*)(t1k + c * 32 + ht * 16);
        const f32x4 c2 = *(const f32x4*)(t2k + c * 32 + ht * 16);
        f32x4 v = a1[ht][r];
        float e0 = fast_tanh(fmaf(rs[r], v[0], fmaf(-rm[r], c1[0], c2[0])));
        float e1 = fast_tanh(fmaf(rs[r], v[1], fmaf(-rm[r], c1[1], c2[1])));
        float e2 = fast_tanh(fmaf(rs[r], v[2], fmaf(-rm[r], c1[2], c2[2])));
        float e3 = fast_tanh(fmaf(rs[r], v[3], fmaf(-rm[r], c1[3], c2[3])));
        hbw[ht * 2]     = cvt_pk_bf16(e0, e1);
        hbw[ht * 2 + 1] = cvt_pk_bf16(e2, e3);
      }
      hb[r] = __builtin_bit_cast(short8, hbw);
    }
    // fc2 partial: branch-free, SMAX tiles (padded rows are zero weights)
    const unsigned short* w2b = w2f + ((size_t)(k * 16 + c) * 16) * 512 + lane * 8;
    #pragma unroll
    for (int s = 0; s < SMAX; ++s) {
      short8 wb = *(const short8*)(w2b + s * 512);
      #pragma unroll
      for (int r = 0; r < MR; ++r)
        acc2[s][r] = mfma_bf16(wb, hb[r], acc2[s][r]);
    }
  }

  // ---- GLU epilogue: pairs (a,g) adjacent in-lane; op<half gates pad ----
  const float* b2k = b2p + (size_t)k * OPAD;
  const bool plain = (m0 / 2000 == (m0 + MB - 1) / 2000) && (m0 + MB <= MTOT);
  if (plain) {
    #pragma unroll
    for (int s = 0; s < SMAX; ++s) {
      f32x4 bias = *(const f32x4*)(b2k + s * 16 + q4 * 4);
      #pragma unroll
      for (int r = 0; r < MR; ++r) {
        const int tloc = wid * MW + r * 16 + col;
        f32x4 v = acc2[s][r];
        #pragma unroll
        for (int p = 0; p < 2; ++p) {
          float a = v[2 * p] + bias[2 * p];
          float g = v[2 * p + 1] + bias[2 * p + 1];
          int op = s * 8 + q4 * 2 + p;
          if (op < half) {
            int orr = op / 6, occ = op - orr * 6;
            Ls[(orr * MB + tloc) * 6 + occ] = a * fast_sigmoid(g);
          }
        }
      }
    }
    __syncthreads();
    const int bb = m0 / 2000;
    const int tb = m0 - bb * 2000;
    const size_t obase = ((size_t)bb * 257 + boffk) * 2000;
    const int tot = bw * MR * 192;     // u64 chunks
    for (int ii = tid; ii < tot; ii += 256) {
      int orr = ii / (MR * 192);
      int rem = ii - orr * (MR * 192);
      *(unsigned long long*)(out + (obase + (size_t)orr * 2000 + tb) * 6 + rem * 2) =
          *(const unsigned long long*)(Ls + orr * (MR * 384) + rem * 2);
    }
  } else {
    // boundary/tail blocks: scatter store
    #pragma unroll
    for (int s = 0; s < SMAX; ++s) {
      f32x4 bias = *(const f32x4*)(b2k + s * 16 + q4 * 4);
      #pragma unroll
      for (int r = 0; r < MR; ++r) {
        const int m = m0 + wid * MW + r * 16 + col;
        f32x4 v = acc2[s][r];
        #pragma unroll
        for (int p = 0; p < 2; ++p) {
          float a = v[2 * p] + bias[2 * p];
          float g = v[2 * p + 1] + bias[2 * p + 1];
          int op = s * 8 + q4 * 2 + p;
          if (op < half && m < MTOT) {
            int bbm = m / 2000;
            int t = m - bbm * 2000;
            int orr = op / 6, occ = op - orr * 6;
            out[(((size_t)bbm * 257 + boffk + orr) * TDIM + t) * 6 + occ] =
                a * fast_sigmoid(g);
          }
        }
      }
    }
  }
}

extern "C" void kernel_launch(void* const* d_in, const int* in_sizes, int n_in,
                              void* d_out, int out_size, void* d_ws, size_t ws_size,
                              hipStream_t stream) {
  const float* x      = (const float*)d_in[0];
  const float* norm_w = (const float*)d_in[1];
  const float* norm_b = (const float*)d_in[2];
  const float* fc1_w  = (const float*)d_in[3];
  const float* fc1_b  = (const float*)d_in[4];
  const float* fc2_w  = (const float*)d_in[5];
  const float* fc2_b  = (const float*)d_in[6];
  float* out = (float*)d_out;
  char* ws = (char*)d_ws;

  float* wsum  = (float*)(ws);
  float* wsq   = (float*)(ws + 512);
  float* gmean = (float*)(ws + 1024);
  float* grstd = (float*)(ws + 1536);
  size_t off = 4096;
  unsigned short* xtf = (unsigned short*)(ws + off); off += (size_t)NBANDS * NMTILE * 4 * 512 * 2;
  unsigned short* w1f = (unsigned short*)(ws + off); off += (size_t)NBANDS * 4 * 8 * 4 * 512 * 2;
  float* t1p = (float*)(ws + off); off += (size_t)NBANDS * HDIM * 4;
  float* t2p = (float*)(ws + off); off += (size_t)NBANDS * HDIM * 4;
  unsigned short* w2f = (unsigned short*)(ws + off); off += (size_t)NBANDS * 16 * 16 * 512 * 2;
  float* b2p = (float*)(ws + off); off += (size_t)NBANDS * OPAD * 4;

  hipMemsetAsync(ws, 0, 1024, stream);
  hipLaunchKernelGGL(k_prep_w1, dim3(NBANDS * HDIM), dim3(128), 0, stream,
                     fc1_w, norm_w, norm_b, fc1_b, w1f, t1p, t2p);
  hipLaunchKernelGGL(k_prep_w2, dim3(NBANDS * 256), dim3(256), 0, stream,
                     fc2_w, fc2_b, w2f, b2p);
  hipLaunchKernelGGL(k_transpose, dim3(250, 4), dim3(256), 0, stream, x, xtf, wsum, wsq);
  hipLaunchKernelGGL(k_finalize, dim3(1), dim3(128), 0, stream, wsum, wsq, gmean, grstd);

  // band classes: k 0..10 (SMAX=3, 32m/wave), 11..22 (SMAX=6, 32m/wave),
  // 23..30 (SMAX=13, 16m/wave to keep VGPR ~110)
  hipFuncSetAttribute((const void*)k_gemm<13,1,125>, hipFuncAttributeMaxDynamicSharedMemorySize, 26112);
  hipFuncSetAttribute((const void*)k_gemm<6,2,63>,   hipFuncAttributeMaxDynamicSharedMemorySize, 24576);
  hipFuncSetAttribute((const void*)k_gemm<3,2,63>,   hipFuncAttributeMaxDynamicSharedMemorySize, 9216);
  hipLaunchKernelGGL((k_gemm<13,1,125>), dim3(8 * 125), dim3(256), 26112, stream,
                     xtf, w1f, t1p, t2p, w2f, b2p, gmean, grstd, out, 23, 8 * 125);
  hipLaunchKernelGGL((k_gemm<6,2,63>),   dim3(12 * 63), dim3(256), 24576, stream,
                     xtf, w1f, t1p, t2p, w2f, b2p, gmean, grstd, out, 11, 12 * 63);
  hipLaunchKernelGGL((k_gemm<3,2,63>),   dim3(11 * 63), dim3(256), 9216, stream,
                     xtf, w1f, t1p, t2p, w2f, b2p, gmean, grstd, out, 0,  11 * 63);
}

// Round 10
// 194.898 us; speedup vs baseline: 1.9425x; 1.4799x over previous
//
#include <hip/hip_runtime.h>
#include <hip/hip_bf16.h>

#define NBANDS 31
#define CDIM 128
#define TDIM 2000
#define HDIM 512
#define MTOT 8000
#define MAXO 204
#define OPAD 224       // b2 bias padded length
#define NGRP 124
#define NMTILE 504     // padded 16-row m-tiles per band
#define NMBK 63        // 128-row m-blocks per band

typedef __attribute__((ext_vector_type(8))) short short8;
typedef __attribute__((ext_vector_type(4))) float f32x4;
typedef __attribute__((ext_vector_type(4))) unsigned int u32x4;
typedef __bf16 bf16x8 __attribute__((ext_vector_type(8)));

__constant__ int d_bw[NBANDS]   = {2,3,3,3,3,3,3,3,3,3,3,8,8,8,8,8,8,8,8,8,8,8,8,16,16,16,16,16,16,16,17};
__constant__ int d_boff[NBANDS] = {0,2,5,8,11,14,17,20,23,26,29,32,40,48,56,64,72,80,88,96,104,112,120,128,144,160,176,192,208,224,240};
__constant__ int d_nn16[NBANDS] = {2,3,3,3,3,3,3,3,3,3,3,6,6,6,6,6,6,6,6,6,6,6,6,12,12,12,12,12,12,12,13};

__device__ __forceinline__ unsigned short f2bf(float f) {
  unsigned int u = __float_as_uint(f);
  return (unsigned short)((u + 0x7fffu + ((u >> 16) & 1u)) >> 16);
}

// packed f32x2 -> bf16x2 (RNE); no builtin on gfx950 (T12)
__device__ __forceinline__ unsigned int cvt_pk_bf16(float lo, float hi) {
  unsigned int r;
  asm("v_cvt_pk_bf16_f32 %0, %1, %2" : "=v"(r) : "v"(lo), "v"(hi));
  return r;
}

// tanh(x) = 1 - 2/(exp2(2*log2e*x)+1)
__device__ __forceinline__ float fast_tanh(float x) {
  float p = __builtin_amdgcn_exp2f(2.885390082f * x);
  return 1.0f - 2.0f * __builtin_amdgcn_rcpf(p + 1.0f);
}

__device__ __forceinline__ float fast_sigmoid(float x) {
  return __builtin_amdgcn_rcpf(1.0f + __builtin_amdgcn_exp2f(-1.442695041f * x));
}

__device__ __forceinline__ f32x4 mfma_bf16(short8 a, short8 b, f32x4 c) {
  return __builtin_amdgcn_mfma_f32_16x16x32_bf16(
      __builtin_bit_cast(bf16x8, a), __builtin_bit_cast(bf16x8, b), c, 0, 0, 0);
}

// direct global->LDS DMA: 64 lanes x 16B = 1KB per call; LDS dst is
// wave-uniform base (HW adds lane*16), global src is per-lane.
__device__ __forceinline__ void g2lds(const char* gsrc, char* ldst, int lane) {
  __builtin_amdgcn_global_load_lds(
      (const __attribute__((address_space(1))) unsigned int*)(gsrc + lane * 16),
      (__attribute__((address_space(3))) unsigned int*)ldst, 16, 0, 0);
}

// ------------- finalize group stats -------------
__global__ void k_finalize(const float* __restrict__ wsum, const float* __restrict__ wsq,
                           float* __restrict__ gmean, float* __restrict__ grstd) {
  int g = threadIdx.x;
  if (g < NGRP) {
    const float n = (float)(CDIM * TDIM);
    float m = wsum[g] / n;
    float v = wsq[g] / n - m * m;
    gmean[g] = m;
    grstd[g] = rsqrtf(v + 1e-5f);
  }
}

// ------------- prep fc1: fold norm affine, MFMA-A fragment order ------------
// w1f: [k][nc 4][hh 8][kk 4][lane 64][8e]; lane l = (h&15)|(q<<4) holds
//   W1fold[h][c = kk*32 + q*8 + j]
__global__ void k_prep_w1(const float* __restrict__ fc1_w, const float* __restrict__ norm_w,
                          const float* __restrict__ norm_b, const float* __restrict__ fc1_b,
                          unsigned short* __restrict__ w1f, float* __restrict__ t1,
                          float* __restrict__ t2) {
  int kn = blockIdx.x;              // k*512 + n(h)
  int k = kn >> 9, n = kn & 511;
  int c = threadIdx.x;              // 128 threads
  float w  = fc1_w[(size_t)kn * CDIM + c];
  float nw = norm_w[k * CDIM + c];
  float nb = norm_b[k * CDIM + c];
  float wp = w * nw;
  {
    int nc = n >> 7, hh = (n >> 4) & 7, kk = c >> 5;
    int lnw = (n & 15) | (((c >> 3) & 3) << 4);
    size_t eoff = ((((size_t)(k * 4 + nc) * 8 + hh) * 4 + kk) * 64 + lnw) * 8 + (c & 7);
    w1f[eoff] = f2bf(wp);
  }
  float s1 = wp, s2 = w * nb;
  #pragma unroll
  for (int off = 32; off >= 1; off >>= 1) {
    s1 += __shfl_down(s1, off);
    s2 += __shfl_down(s2, off);
  }
  __shared__ float r1[2], r2[2];
  if ((threadIdx.x & 63) == 0) { r1[threadIdx.x >> 6] = s1; r2[threadIdx.x >> 6] = s2; }
  __syncthreads();
  if (threadIdx.x == 0) {
    t1[kn] = r1[0] + r1[1];
    t2[kn] = r2[0] + r2[1] + fc1_b[kn];
  }
}

// ------------- prep fc2: GLU-pair permute + pi(k) column permute ------------
// w2f: [k][ks 16][ot 16][lane 64][8e].  Within each 32-h k-step the column
// order is pi(k) = ((k>>2)&1)*16 + (k>>3)*4 + (k&3), matching fc1's C-frag
// consumed directly as fc2's B-frag.  Rows o >= 12*bw are ZERO.
__global__ void k_prep_w2(const float* __restrict__ fc2_w, const float* __restrict__ fc2_b,
                          unsigned short* __restrict__ w2f, float* __restrict__ b2) {
  int ko = blockIdx.x;              // k*256 + o
  int k = ko >> 8;
  int o = ko & 255;
  int bw = d_bw[k];
  int O2 = 12 * bw, hf = 6 * bw;
  bool valid = o < O2;
  int srcrow = valid ? ((o & 1) ? (hf + (o >> 1)) : (o >> 1)) : 0;
  const float* sp = fc2_w + ((size_t)k * MAXO + srcrow) * HDIM;
  if (threadIdx.x == 0 && o < OPAD)
    b2[k * OPAD + o] = valid ? fc2_b[k * MAXO + srcrow] : 0.f;
  int ot = o >> 4, rr = o & 15;
  for (int j = threadIdx.x; j < HDIM; j += 256) {
    int ks = j >> 5, hp = j & 31;
    int q  = (hp >> 2) & 3;                 // inverse of pi: lane quad
    int jj = ((hp >> 4) << 2) | (hp & 3);   // elem = ht*4 + r
    unsigned short val = valid ? f2bf(sp[j]) : (unsigned short)0;
    size_t eoff = (((size_t)(k * 16 + ks)) * 16 + ot) * 512 + (size_t)(rr | (q << 4)) * 8 + jj;
    w2f[eoff] = val;
  }
}

// ------------- transpose x[B,C,T,K] -> xtf fragment order, fused stats ------
__global__ void k_transpose(const float* __restrict__ x, unsigned short* __restrict__ xtf,
                            float* __restrict__ wsum, float* __restrict__ wsq) {
  __shared__ unsigned short tile[248 * 128];   // rows staggered by 4f bytes
  __shared__ float sred[256], sqred[256];
  const int t0 = blockIdx.x * 8;
  const int b = blockIdx.y;
  const int tid = threadIdx.x;
  const float* p = x + ((size_t)b * CDIM * TDIM + t0) * NBANDS;
  float s = 0.f, sq = 0.f;
  if (tid < 248) {
    const int f = tid;
    char* row = (char*)tile + f * 256;
    const int st = 4 * f;
    #pragma unroll 4
    for (int c2 = 0; c2 < 64; ++c2) {
      float v0 = p[(size_t)c2 * 124000 + f];
      float v1 = p[(size_t)c2 * 124000 + 62000 + f];
      s += v0 + v1;
      sq += v0 * v0 + v1 * v1;
      *(unsigned int*)(row + ((4 * c2 + st) & 255)) = cvt_pk_bf16(v0, v1);
    }
  }
  sred[tid] = s; sqred[tid] = sq;
  __syncthreads();
  if (tid < 31) {
    float ss = 0.f, qs = 0.f;
    #pragma unroll
    for (int j = 0; j < 8; ++j) { ss += sred[tid + 31 * j]; qs += sqred[tid + 31 * j]; }
    atomicAdd(&wsum[b * 31 + tid], ss);
    atomicAdd(&wsq [b * 31 + tid], qs);
  }
  for (int idx = tid; idx < 3968; idx += 256) {
    int ti = idx & 7, q4w = (idx >> 3) & 3, kkw = (idx >> 5) & 3, kb = idx >> 7;
    int f = ti * 31 + kb;
    const char* row = (const char*)tile + f * 256;
    const int st = 4 * f;
    u32x4 v;
    #pragma unroll
    for (int j = 0; j < 4; ++j)
      v[j] = *(const unsigned int*)(row + ((kkw * 64 + q4w * 16 + 4 * j + st) & 255));
    int m = b * TDIM + t0 + ti;
    int mtile = m >> 4, mrow = m & 15;
    size_t eoff = ((((size_t)kb * NMTILE + mtile) * 4 + kkw) * 64 + (mrow | (q4w << 4))) * 8;
    *(u32x4*)(xtf + eoff) = v;
  }
}

// ------------- fused GEMM: LDS-staged weights (global_load_lds 2-phase) -----
// Weights for chunk c+1 DMA'd global->LDS (zero VGPRs, 1 instr/KB, 4 waves
// split the tiles); compute reads ds_read_b128 (~64cy vs ~300cy L2).  R5-R9
// plateau was per-wave L2 load streams with tiny VGPR staging budget
// (VGPR_Count=52: compiler gives accs AGPRs, leaves no regs for load depth).
// Keeps: pi(k) zero-shuffle fc1->fc2 handoff, X in regs, MR=2, 3-class split.
template<int SMAX>
__launch_bounds__(256, 2)
__global__ void k_gemm(const unsigned short* __restrict__ xtf,
                       const unsigned short* __restrict__ w1f,
                       const float* __restrict__ t1p, const float* __restrict__ t2p,
                       const unsigned short* __restrict__ w2f,
                       const float* __restrict__ b2p,
                       const float* __restrict__ gmean, const float* __restrict__ grstd,
                       float* __restrict__ out, int kbase, int nwg) {
  extern __shared__ char lds[];
  constexpr int BUFB = (8 + SMAX) * 1024;
  float* const t12 = (float*)lds;          // 4 KB: t1[512] | t2[512]
  char* const bufA = lds + 4096;
  char* const bufB = lds + 4096 + BUFB;
  float* const Ls  = (float*)lds;          // epilogue reuse

  // bijective XCD-aware swizzle
  const int bid = blockIdx.x;
  const int qq = nwg >> 3, r8 = nwg & 7;
  const int xcd = bid & 7, ixd = bid >> 3;
  const int wg = (xcd < r8 ? xcd * (qq + 1) : r8 * (qq + 1) + (xcd - r8) * qq) + ixd;
  const int kl = wg / NMBK;
  const int k = kbase + kl;
  const int mb = wg - kl * NMBK;
  const int m0 = mb * 128;

  const int tid = threadIdx.x;
  const int lane = tid & 63;
  const int wid = tid >> 6;          // 4 waves, 32 m-rows each (MR=2)
  const int col = lane & 15;
  const int q4 = lane >> 4;

  const int bw = d_bw[k];
  const int nn = d_nn16[k];          // <= SMAX
  const int half = 6 * bw;
  const int boffk = d_boff[k];

  // t1/t2 -> LDS (1 KB per 256 threads x2 arrays x2 halves)
  #pragma unroll
  for (int i = 0; i < 2; ++i) {
    t12[tid + i * 256] = t1p[k * HDIM + tid + i * 256];
    t12[512 + tid + i * 256] = t2p[k * HDIM + tid + i * 256];
  }

  // X fragments in registers for the whole kernel (32 VGPR)
  const int mt0 = (m0 >> 4) + wid * 2;
  short8 xv[2][4];
  #pragma unroll
  for (int r = 0; r < 2; ++r)
    #pragma unroll
    for (int kk = 0; kk < 4; ++kk)
      xv[r][kk] = *(const short8*)(xtf +
          (((size_t)k * NMTILE + mt0 + r) * 4 + kk) * 512 + lane * 8);

  // norm constants (acc col = m = lane&15)
  float rs[2], rm[2];
  #pragma unroll
  for (int r = 0; r < 2; ++r) {
    int mr = m0 + wid * 32 + r * 16 + col;
    int mc = mr < (MTOT - 1) ? mr : (MTOT - 1);
    int g = (mc / 2000) * NBANDS + k;
    rs[r] = grstd[g];
    rm[r] = rs[r] * gmean[g];
  }

  const char* const w1kc = (const char*)w1f + (size_t)k * 131072;
  const char* const w2kc = (const char*)w2f + (size_t)k * 262144;
  const int ntt = 8 + nn;            // staged 1KB tiles per chunk

  // stage weights for chunk c: w1 8KB (2 hh-tiles x 4 kk) + w2 nn KB
  auto stage = [&](char* buf, int c) {
    const char* w1c = w1kc + (((c >> 2) * 8 + (c & 3) * 2) * 4096);
    const char* w2c = w2kc + c * 16384;
    for (int t = wid; t < ntt; t += 4) {   // wave-uniform t
      const char* src = (t < 8) ? (w1c + t * 1024) : (w2c + (t - 8) * 1024);
      g2lds(src, buf + t * 1024, lane);
    }
  };

  const f32x4 fz = {0.f, 0.f, 0.f, 0.f};
  f32x4 acc2[SMAX][2];
  #pragma unroll
  for (int s = 0; s < SMAX; ++s) { acc2[s][0] = fz; acc2[s][1] = fz; }

  stage(bufA, 0);
  __syncthreads();                   // drains vmcnt -> buf0 + t12 visible

  #pragma unroll 1
  for (int c = 0; c < 16; ++c) {     // 16 chunks of 32 h
    char* const bc = (c & 1) ? bufB : bufA;
    if (c < 15) stage((c & 1) ? bufA : bufB, c + 1);  // buf[c+1&1] free since c-1's barrier

    // ---- fc1 from LDS ----
    f32x4 a1[2][2];
    a1[0][0] = fz; a1[0][1] = fz; a1[1][0] = fz; a1[1][1] = fz;
    #pragma unroll
    for (int kk = 0; kk < 4; ++kk) {
      short8 wa0 = *(const short8*)(bc + kk * 1024 + lane * 16);
      short8 wa1 = *(const short8*)(bc + 4096 + kk * 1024 + lane * 16);
      #pragma unroll
      for (int r = 0; r < 2; ++r) {
        a1[0][r] = mfma_bf16(wa0, xv[r][kk], a1[0][r]);
        a1[1][r] = mfma_bf16(wa1, xv[r][kk], a1[1][r]);
      }
    }
    // ---- tanh epilogue -> B-frag in-lane (pi(k) order) ----
    short8 hb[2];
    #pragma unroll
    for (int r = 0; r < 2; ++r) {
      u32x4 hbw;
      #pragma unroll
      for (int ht = 0; ht < 2; ++ht) {
        const f32x4 c1 = *(const f32x4*)(t12 + c * 32 + ht * 16 + q4 * 4);
        const f32x4 c2 = *(const f32x4*)(t12 + 512 + c * 32 + ht * 16 + q4 * 4);
        f32x4 v = a1[ht][r];
        float e0 = fast_tanh(fmaf(rs[r], v[0], fmaf(-rm[r], c1[0], c2[0])));
        float e1 = fast_tanh(fmaf(rs[r], v[1], fmaf(-rm[r], c1[1], c2[1])));
        float e2 = fast_tanh(fmaf(rs[r], v[2], fmaf(-rm[r], c1[2], c2[2])));
        float e3 = fast_tanh(fmaf(rs[r], v[3], fmaf(-rm[r], c1[3], c2[3])));
        hbw[ht * 2]     = cvt_pk_bf16(e0, e1);
        hbw[ht * 2 + 1] = cvt_pk_bf16(e2, e3);
      }
      hb[r] = __builtin_bit_cast(short8, hbw);
    }
    // ---- fc2 from LDS (static unroll, wave-uniform guard; rule #20) ----
    const char* w2l = bc + 8192;
    #pragma unroll
    for (int s = 0; s < SMAX; ++s) {
      if (s < nn) {
        short8 wb = *(const short8*)(w2l + s * 1024 + lane * 16);
        acc2[s][0] = mfma_bf16(wb, hb[0], acc2[s][0]);
        acc2[s][1] = mfma_bf16(wb, hb[1], acc2[s][1]);
      }
    }
    __syncthreads();                 // drains this wave's stage; syncs readers
  }

  // ---- GLU epilogue: pairs (a,g) adjacent in-lane ----
  const float* b2k = b2p + (size_t)k * OPAD;
  const bool plain = (m0 / 2000 == (m0 + 127) / 2000) && (m0 + 128 <= MTOT);
  if (plain) {
    #pragma unroll
    for (int s = 0; s < SMAX; ++s) {
      if (s < nn) {
        f32x4 bias = *(const f32x4*)(b2k + s * 16 + q4 * 4);
        #pragma unroll
        for (int r = 0; r < 2; ++r) {
          const int tloc = wid * 32 + r * 16 + col;
          f32x4 v = acc2[s][r];
          #pragma unroll
          for (int p = 0; p < 2; ++p) {
            float a = v[2 * p] + bias[2 * p];
            float g = v[2 * p + 1] + bias[2 * p + 1];
            int op = s * 8 + q4 * 2 + p;
            if (op < half) {
              int orr = op / 6, occ = op - orr * 6;
              Ls[(orr * 128 + tloc) * 6 + occ] = a * fast_sigmoid(g);
            }
          }
        }
      }
    }
    __syncthreads();
    const int bb = m0 / 2000;
    const int tb = m0 - bb * 2000;
    const size_t obase = ((size_t)bb * 257 + boffk) * 2000;
    const int tot = bw * 384;          // u64 chunks (128 tok * 6 f32 / 2)
    for (int ii = tid; ii < tot; ii += 256) {
      int orr = ii / 384;
      int rem = ii - orr * 384;
      *(unsigned long long*)(out + (obase + (size_t)orr * 2000 + tb) * 6 + rem * 2) =
          *(const unsigned long long*)(Ls + orr * 768 + rem * 2);
    }
  } else {
    // boundary/tail blocks: scatter store
    #pragma unroll
    for (int s = 0; s < SMAX; ++s) {
      if (s < nn) {
        f32x4 bias = *(const f32x4*)(b2k + s * 16 + q4 * 4);
        #pragma unroll
        for (int r = 0; r < 2; ++r) {
          const int m = m0 + wid * 32 + r * 16 + col;
          f32x4 v = acc2[s][r];
          #pragma unroll
          for (int p = 0; p < 2; ++p) {
            float a = v[2 * p] + bias[2 * p];
            float g = v[2 * p + 1] + bias[2 * p + 1];
            int op = s * 8 + q4 * 2 + p;
            if (op < half && m < MTOT) {
              int bbm = m / 2000;
              int t = m - bbm * 2000;
              int orr = op / 6, occ = op - orr * 6;
              out[(((size_t)bbm * 257 + boffk + orr) * TDIM + t) * 6 + occ] =
                  a * fast_sigmoid(g);
            }
          }
        }
      }
    }
  }
}

extern "C" void kernel_launch(void* const* d_in, const int* in_sizes, int n_in,
                              void* d_out, int out_size, void* d_ws, size_t ws_size,
                              hipStream_t stream) {
  const float* x      = (const float*)d_in[0];
  const float* norm_w = (const float*)d_in[1];
  const float* norm_b = (const float*)d_in[2];
  const float* fc1_w  = (const float*)d_in[3];
  const float* fc1_b  = (const float*)d_in[4];
  const float* fc2_w  = (const float*)d_in[5];
  const float* fc2_b  = (const float*)d_in[6];
  float* out = (float*)d_out;
  char* ws = (char*)d_ws;

  float* wsum  = (float*)(ws);
  float* wsq   = (float*)(ws + 512);
  float* gmean = (float*)(ws + 1024);
  float* grstd = (float*)(ws + 1536);
  size_t off = 4096;
  unsigned short* xtf = (unsigned short*)(ws + off); off += (size_t)NBANDS * NMTILE * 4 * 512 * 2;
  unsigned short* w1f = (unsigned short*)(ws + off); off += (size_t)NBANDS * 4 * 8 * 4 * 512 * 2;
  float* t1p = (float*)(ws + off); off += (size_t)NBANDS * HDIM * 4;
  float* t2p = (float*)(ws + off); off += (size_t)NBANDS * HDIM * 4;
  unsigned short* w2f = (unsigned short*)(ws + off); off += (size_t)NBANDS * 16 * 16 * 512 * 2;
  float* b2p = (float*)(ws + off); off += (size_t)NBANDS * OPAD * 4;

  hipMemsetAsync(ws, 0, 1024, stream);
  hipLaunchKernelGGL(k_prep_w1, dim3(NBANDS * HDIM), dim3(128), 0, stream,
                     fc1_w, norm_w, norm_b, fc1_b, w1f, t1p, t2p);
  hipLaunchKernelGGL(k_prep_w2, dim3(NBANDS * 256), dim3(256), 0, stream,
                     fc2_w, fc2_b, w2f, b2p);
  hipLaunchKernelGGL(k_transpose, dim3(250, 4), dim3(256), 0, stream, x, xtf, wsum, wsq);
  hipLaunchKernelGGL(k_finalize, dim3(1), dim3(128), 0, stream, wsum, wsq, gmean, grstd);

  // dyn LDS: 4KB t12 + 2 x (8+SMAX)KB bufs; epilogue Ls = bw*128*6*4 reuses base
  hipFuncSetAttribute((const void*)k_gemm<13>, hipFuncAttributeMaxDynamicSharedMemorySize, 52224);
  hipFuncSetAttribute((const void*)k_gemm<6>,  hipFuncAttributeMaxDynamicSharedMemorySize, 32768);
  hipFuncSetAttribute((const void*)k_gemm<3>,  hipFuncAttributeMaxDynamicSharedMemorySize, 26624);
  hipLaunchKernelGGL((k_gemm<13>), dim3(8 * NMBK),  dim3(256), 52224, stream,
                     xtf, w1f, t1p, t2p, w2f, b2p, gmean, grstd, out, 23, 8 * NMBK);
  hipLaunchKernelGGL((k_gemm<6>),  dim3(12 * NMBK), dim3(256), 32768, stream,
                     xtf, w1f, t1p, t2p, w2f, b2p, gmean, grstd, out, 11, 12 * NMBK);
  hipLaunchKernelGGL((k_gemm<3>),  dim3(11 * NMBK), dim3(256), 26624, stream,
                     xtf, w1f, t1p, t2p, w2f, b2p, gmean, grstd, out, 0,  11 * NMBK);
}

// Round 11
// 187.859 us; speedup vs baseline: 2.0153x; 1.0375x over previous
//
#include <hip/hip_runtime.h>
#include <hip/hip_bf16.h>

#define NBANDS 31
#define CDIM 128
#define TDIM 2000
#define HDIM 512
#define MTOT 8000
#define MAXO 204
#define OPAD 224       // b2 bias padded length
#define NGRP 124
#define NMTILE 504     // padded 16-row m-tiles per band
#define NMBK 63        // 128-row m-blocks per band

typedef __attribute__((ext_vector_type(8))) short short8;
typedef __attribute__((ext_vector_type(4))) float f32x4;
typedef __attribute__((ext_vector_type(4))) unsigned int u32x4;
typedef __bf16 bf16x8 __attribute__((ext_vector_type(8)));

__constant__ int d_bw[NBANDS]   = {2,3,3,3,3,3,3,3,3,3,3,8,8,8,8,8,8,8,8,8,8,8,8,16,16,16,16,16,16,16,17};
__constant__ int d_boff[NBANDS] = {0,2,5,8,11,14,17,20,23,26,29,32,40,48,56,64,72,80,88,96,104,112,120,128,144,160,176,192,208,224,240};
__constant__ int d_nn16[NBANDS] = {2,3,3,3,3,3,3,3,3,3,3,6,6,6,6,6,6,6,6,6,6,6,6,12,12,12,12,12,12,12,13};

__device__ __forceinline__ unsigned short f2bf(float f) {
  unsigned int u = __float_as_uint(f);
  return (unsigned short)((u + 0x7fffu + ((u >> 16) & 1u)) >> 16);
}

// packed f32x2 -> bf16x2 (RNE); no builtin on gfx950 (T12)
__device__ __forceinline__ unsigned int cvt_pk_bf16(float lo, float hi) {
  unsigned int r;
  asm("v_cvt_pk_bf16_f32 %0, %1, %2" : "=v"(r) : "v"(lo), "v"(hi));
  return r;
}

// tanh(x) = 1 - 2/(exp2(2*log2e*x)+1)
__device__ __forceinline__ float fast_tanh(float x) {
  float p = __builtin_amdgcn_exp2f(2.885390082f * x);
  return 1.0f - 2.0f * __builtin_amdgcn_rcpf(p + 1.0f);
}

__device__ __forceinline__ float fast_sigmoid(float x) {
  return __builtin_amdgcn_rcpf(1.0f + __builtin_amdgcn_exp2f(-1.442695041f * x));
}

__device__ __forceinline__ f32x4 mfma_bf16(short8 a, short8 b, f32x4 c) {
  return __builtin_amdgcn_mfma_f32_16x16x32_bf16(
      __builtin_bit_cast(bf16x8, a), __builtin_bit_cast(bf16x8, b), c, 0, 0, 0);
}

// direct global->LDS DMA: 64 lanes x 16B = 1KB per call; LDS dst is
// wave-uniform base (HW adds lane*16), global src is per-lane.
__device__ __forceinline__ void g2lds(const char* gsrc, char* ldst, int lane) {
  __builtin_amdgcn_global_load_lds(
      (const __attribute__((address_space(1))) unsigned int*)(gsrc + lane * 16),
      (__attribute__((address_space(3))) unsigned int*)ldst, 16, 0, 0);
}

// ------------- finalize group stats -------------
__global__ void k_finalize(const float* __restrict__ wsum, const float* __restrict__ wsq,
                           float* __restrict__ gmean, float* __restrict__ grstd) {
  int g = threadIdx.x;
  if (g < NGRP) {
    const float n = (float)(CDIM * TDIM);
    float m = wsum[g] / n;
    float v = wsq[g] / n - m * m;
    gmean[g] = m;
    grstd[g] = rsqrtf(v + 1e-5f);
  }
}

// ------------- prep fc1: fold norm affine, MFMA-A fragment order ------------
// w1f: [k][nc 4][hh 8][kk 4][lane 64][8e]; lane l = (h&15)|(q<<4) holds
//   W1fold[h][c = kk*32 + q*8 + j].  Block 0 also zeroes wsum/wsq (replaces
//   a 1KB hipMemsetAsync whose fill kernel cost ~73us/replay in R10).
__global__ void k_prep_w1(const float* __restrict__ fc1_w, const float* __restrict__ norm_w,
                          const float* __restrict__ norm_b, const float* __restrict__ fc1_b,
                          unsigned short* __restrict__ w1f, float* __restrict__ t1,
                          float* __restrict__ t2, float* __restrict__ wsum,
                          float* __restrict__ wsq) {
  if (blockIdx.x == 0 && threadIdx.x < NGRP) {
    wsum[threadIdx.x] = 0.f;
    wsq[threadIdx.x] = 0.f;
  }
  int kn = blockIdx.x;              // k*512 + n(h)
  int k = kn >> 9, n = kn & 511;
  int c = threadIdx.x;              // 128 threads
  float w  = fc1_w[(size_t)kn * CDIM + c];
  float nw = norm_w[k * CDIM + c];
  float nb = norm_b[k * CDIM + c];
  float wp = w * nw;
  {
    int nc = n >> 7, hh = (n >> 4) & 7, kk = c >> 5;
    int lnw = (n & 15) | (((c >> 3) & 3) << 4);
    size_t eoff = ((((size_t)(k * 4 + nc) * 8 + hh) * 4 + kk) * 64 + lnw) * 8 + (c & 7);
    w1f[eoff] = f2bf(wp);
  }
  float s1 = wp, s2 = w * nb;
  #pragma unroll
  for (int off = 32; off >= 1; off >>= 1) {
    s1 += __shfl_down(s1, off);
    s2 += __shfl_down(s2, off);
  }
  __shared__ float r1[2], r2[2];
  if ((threadIdx.x & 63) == 0) { r1[threadIdx.x >> 6] = s1; r2[threadIdx.x >> 6] = s2; }
  __syncthreads();
  if (threadIdx.x == 0) {
    t1[kn] = r1[0] + r1[1];
    t2[kn] = r2[0] + r2[1] + fc1_b[kn];
  }
}

// ------------- prep fc2: GLU-pair permute + pi(k) column permute ------------
// w2f: [k][ks 16][ot 16][lane 64][8e].  Within each 32-h k-step the column
// order is pi(k) = ((k>>2)&1)*16 + (k>>3)*4 + (k&3), matching fc1's C-frag
// consumed directly as fc2's B-frag.  Rows o >= 12*bw are ZERO.
__global__ void k_prep_w2(const float* __restrict__ fc2_w, const float* __restrict__ fc2_b,
                          unsigned short* __restrict__ w2f, float* __restrict__ b2) {
  int ko = blockIdx.x;              // k*256 + o
  int k = ko >> 8;
  int o = ko & 255;
  int bw = d_bw[k];
  int O2 = 12 * bw, hf = 6 * bw;
  bool valid = o < O2;
  int srcrow = valid ? ((o & 1) ? (hf + (o >> 1)) : (o >> 1)) : 0;
  const float* sp = fc2_w + ((size_t)k * MAXO + srcrow) * HDIM;
  if (threadIdx.x == 0 && o < OPAD)
    b2[k * OPAD + o] = valid ? fc2_b[k * MAXO + srcrow] : 0.f;
  int ot = o >> 4, rr = o & 15;
  for (int j = threadIdx.x; j < HDIM; j += 256) {
    int ks = j >> 5, hp = j & 31;
    int q  = (hp >> 2) & 3;                 // inverse of pi: lane quad
    int jj = ((hp >> 4) << 2) | (hp & 3);   // elem = ht*4 + r
    unsigned short val = valid ? f2bf(sp[j]) : (unsigned short)0;
    size_t eoff = (((size_t)(k * 16 + ks)) * 16 + ot) * 512 + (size_t)(rr | (q << 4)) * 8 + jj;
    w2f[eoff] = val;
  }
}

// ------------- transpose x[B,C,T,K] -> xtf fragment order, fused stats ------
__global__ void k_transpose(const float* __restrict__ x, unsigned short* __restrict__ xtf,
                            float* __restrict__ wsum, float* __restrict__ wsq) {
  __shared__ unsigned short tile[248 * 128];   // rows staggered by 4f bytes
  __shared__ float sred[256], sqred[256];
  const int t0 = blockIdx.x * 8;
  const int b = blockIdx.y;
  const int tid = threadIdx.x;
  const float* p = x + ((size_t)b * CDIM * TDIM + t0) * NBANDS;
  float s = 0.f, sq = 0.f;
  if (tid < 248) {
    const int f = tid;
    char* row = (char*)tile + f * 256;
    const int st = 4 * f;
    #pragma unroll 4
    for (int c2 = 0; c2 < 64; ++c2) {
      float v0 = p[(size_t)c2 * 124000 + f];
      float v1 = p[(size_t)c2 * 124000 + 62000 + f];
      s += v0 + v1;
      sq += v0 * v0 + v1 * v1;
      *(unsigned int*)(row + ((4 * c2 + st) & 255)) = cvt_pk_bf16(v0, v1);
    }
  }
  sred[tid] = s; sqred[tid] = sq;
  __syncthreads();
  if (tid < 31) {
    float ss = 0.f, qs = 0.f;
    #pragma unroll
    for (int j = 0; j < 8; ++j) { ss += sred[tid + 31 * j]; qs += sqred[tid + 31 * j]; }
    atomicAdd(&wsum[b * 31 + tid], ss);
    atomicAdd(&wsq [b * 31 + tid], qs);
  }
  for (int idx = tid; idx < 3968; idx += 256) {
    int ti = idx & 7, q4w = (idx >> 3) & 3, kkw = (idx >> 5) & 3, kb = idx >> 7;
    int f = ti * 31 + kb;
    const char* row = (const char*)tile + f * 256;
    const int st = 4 * f;
    u32x4 v;
    #pragma unroll
    for (int j = 0; j < 4; ++j)
      v[j] = *(const unsigned int*)(row + ((kkw * 64 + q4w * 16 + 4 * j + st) & 255));
    int m = b * TDIM + t0 + ti;
    int mtile = m >> 4, mrow = m & 15;
    size_t eoff = ((((size_t)kb * NMTILE + mtile) * 4 + kkw) * 64 + (mrow | (q4w << 4))) * 8;
    *(u32x4*)(xtf + eoff) = v;
  }
}

// ------------- fused GEMM: LDS-staged weights (global_load_lds 2-phase) -----
// Weights for chunk c+1 DMA'd global->LDS (zero VGPRs, 1 instr/KB, 4 waves
// split the tiles); compute reads ds_read_b128 (~64cy vs ~300cy L2).
// Keeps: pi(k) zero-shuffle fc1->fc2 handoff, X in regs, MR=2, 3-class split.
template<int SMAX>
__launch_bounds__(256, 2)
__global__ void k_gemm(const unsigned short* __restrict__ xtf,
                       const unsigned short* __restrict__ w1f,
                       const float* __restrict__ t1p, const float* __restrict__ t2p,
                       const unsigned short* __restrict__ w2f,
                       const float* __restrict__ b2p,
                       const float* __restrict__ gmean, const float* __restrict__ grstd,
                       float* __restrict__ out, int kbase, int nwg) {
  extern __shared__ char lds[];
  constexpr int BUFB = (8 + SMAX) * 1024;
  float* const t12 = (float*)lds;          // 4 KB: t1[512] | t2[512]
  char* const bufA = lds + 4096;
  char* const bufB = lds + 4096 + BUFB;
  float* const Ls  = (float*)lds;          // epilogue reuse

  // bijective XCD-aware swizzle
  const int bid = blockIdx.x;
  const int qq = nwg >> 3, r8 = nwg & 7;
  const int xcd = bid & 7, ixd = bid >> 3;
  const int wg = (xcd < r8 ? xcd * (qq + 1) : r8 * (qq + 1) + (xcd - r8) * qq) + ixd;
  const int kl = wg / NMBK;
  const int k = kbase + kl;
  const int mb = wg - kl * NMBK;
  const int m0 = mb * 128;

  const int tid = threadIdx.x;
  const int lane = tid & 63;
  const int wid = tid >> 6;          // 4 waves, 32 m-rows each (MR=2)
  const int col = lane & 15;
  const int q4 = lane >> 4;

  const int bw = d_bw[k];
  const int nn = d_nn16[k];          // <= SMAX
  const int half = 6 * bw;
  const int boffk = d_boff[k];

  // t1/t2 -> LDS (1 KB per 256 threads x2 arrays x2 halves)
  #pragma unroll
  for (int i = 0; i < 2; ++i) {
    t12[tid + i * 256] = t1p[k * HDIM + tid + i * 256];
    t12[512 + tid + i * 256] = t2p[k * HDIM + tid + i * 256];
  }

  // X fragments in registers for the whole kernel (32 VGPR)
  const int mt0 = (m0 >> 4) + wid * 2;
  short8 xv[2][4];
  #pragma unroll
  for (int r = 0; r < 2; ++r)
    #pragma unroll
    for (int kk = 0; kk < 4; ++kk)
      xv[r][kk] = *(const short8*)(xtf +
          (((size_t)k * NMTILE + mt0 + r) * 4 + kk) * 512 + lane * 8);

  // norm constants (acc col = m = lane&15)
  float rs[2], rm[2];
  #pragma unroll
  for (int r = 0; r < 2; ++r) {
    int mr = m0 + wid * 32 + r * 16 + col;
    int mc = mr < (MTOT - 1) ? mr : (MTOT - 1);
    int g = (mc / 2000) * NBANDS + k;
    rs[r] = grstd[g];
    rm[r] = rs[r] * gmean[g];
  }

  const char* const w1kc = (const char*)w1f + (size_t)k * 131072;
  const char* const w2kc = (const char*)w2f + (size_t)k * 262144;
  const int ntt = 8 + nn;            // staged 1KB tiles per chunk

  // stage weights for chunk c: w1 8KB (2 hh-tiles x 4 kk) + w2 nn KB
  auto stage = [&](char* buf, int c) {
    const char* w1c = w1kc + (((c >> 2) * 8 + (c & 3) * 2) * 4096);
    const char* w2c = w2kc + c * 16384;
    for (int t = wid; t < ntt; t += 4) {   // wave-uniform t
      const char* src = (t < 8) ? (w1c + t * 1024) : (w2c + (t - 8) * 1024);
      g2lds(src, buf + t * 1024, lane);
    }
  };

  const f32x4 fz = {0.f, 0.f, 0.f, 0.f};
  f32x4 acc2[SMAX][2];
  #pragma unroll
  for (int s = 0; s < SMAX; ++s) { acc2[s][0] = fz; acc2[s][1] = fz; }

  stage(bufA, 0);
  __syncthreads();                   // drains vmcnt -> buf0 + t12 visible

  #pragma unroll 1
  for (int c = 0; c < 16; ++c) {     // 16 chunks of 32 h
    char* const bc = (c & 1) ? bufB : bufA;
    if (c < 15) stage((c & 1) ? bufA : bufB, c + 1);  // buf[c+1&1] free since c-1's barrier

    // ---- fc1 from LDS ----
    f32x4 a1[2][2];
    a1[0][0] = fz; a1[0][1] = fz; a1[1][0] = fz; a1[1][1] = fz;
    #pragma unroll
    for (int kk = 0; kk < 4; ++kk) {
      short8 wa0 = *(const short8*)(bc + kk * 1024 + lane * 16);
      short8 wa1 = *(const short8*)(bc + 4096 + kk * 1024 + lane * 16);
      #pragma unroll
      for (int r = 0; r < 2; ++r) {
        a1[0][r] = mfma_bf16(wa0, xv[r][kk], a1[0][r]);
        a1[1][r] = mfma_bf16(wa1, xv[r][kk], a1[1][r]);
      }
    }
    // ---- tanh epilogue -> B-frag in-lane (pi(k) order) ----
    short8 hb[2];
    #pragma unroll
    for (int r = 0; r < 2; ++r) {
      u32x4 hbw;
      #pragma unroll
      for (int ht = 0; ht < 2; ++ht) {
        const f32x4 c1 = *(const f32x4*)(t12 + c * 32 + ht * 16 + q4 * 4);
        const f32x4 c2 = *(const f32x4*)(t12 + 512 + c * 32 + ht * 16 + q4 * 4);
        f32x4 v = a1[ht][r];
        float e0 = fast_tanh(fmaf(rs[r], v[0], fmaf(-rm[r], c1[0], c2[0])));
        float e1 = fast_tanh(fmaf(rs[r], v[1], fmaf(-rm[r], c1[1], c2[1])));
        float e2 = fast_tanh(fmaf(rs[r], v[2], fmaf(-rm[r], c1[2], c2[2])));
        float e3 = fast_tanh(fmaf(rs[r], v[3], fmaf(-rm[r], c1[3], c2[3])));
        hbw[ht * 2]     = cvt_pk_bf16(e0, e1);
        hbw[ht * 2 + 1] = cvt_pk_bf16(e2, e3);
      }
      hb[r] = __builtin_bit_cast(short8, hbw);
    }
    // ---- fc2 from LDS (static unroll, wave-uniform guard; rule #20) ----
    const char* w2l = bc + 8192;
    #pragma unroll
    for (int s = 0; s < SMAX; ++s) {
      if (s < nn) {
        short8 wb = *(const short8*)(w2l + s * 1024 + lane * 16);
        acc2[s][0] = mfma_bf16(wb, hb[0], acc2[s][0]);
        acc2[s][1] = mfma_bf16(wb, hb[1], acc2[s][1]);
      }
    }
    __syncthreads();                 // drains this wave's stage; syncs readers
  }

  // ---- GLU epilogue: pairs (a,g) adjacent in-lane ----
  const float* b2k = b2p + (size_t)k * OPAD;
  const bool plain = (m0 / 2000 == (m0 + 127) / 2000) && (m0 + 128 <= MTOT);
  if (plain) {
    #pragma unroll
    for (int s = 0; s < SMAX; ++s) {
      if (s < nn) {
        f32x4 bias = *(const f32x4*)(b2k + s * 16 + q4 * 4);
        #pragma unroll
        for (int r = 0; r < 2; ++r) {
          const int tloc = wid * 32 + r * 16 + col;
          f32x4 v = acc2[s][r];
          #pragma unroll
          for (int p = 0; p < 2; ++p) {
            float a = v[2 * p] + bias[2 * p];
            float g = v[2 * p + 1] + bias[2 * p + 1];
            int op = s * 8 + q4 * 2 + p;
            if (op < half) {
              int orr = op / 6, occ = op - orr * 6;
              Ls[(orr * 128 + tloc) * 6 + occ] = a * fast_sigmoid(g);
            }
          }
        }
      }
    }
    __syncthreads();
    const int bb = m0 / 2000;
    const int tb = m0 - bb * 2000;
    const size_t obase = ((size_t)bb * 257 + boffk) * 2000;
    const int tot = bw * 384;          // u64 chunks (128 tok * 6 f32 / 2)
    for (int ii = tid; ii < tot; ii += 256) {
      int orr = ii / 384;
      int rem = ii - orr * 384;
      *(unsigned long long*)(out + (obase + (size_t)orr * 2000 + tb) * 6 + rem * 2) =
          *(const unsigned long long*)(Ls + orr * 768 + rem * 2);
    }
  } else {
    // boundary/tail blocks: scatter store
    #pragma unroll
    for (int s = 0; s < SMAX; ++s) {
      if (s < nn) {
        f32x4 bias = *(const f32x4*)(b2k + s * 16 + q4 * 4);
        #pragma unroll
        for (int r = 0; r < 2; ++r) {
          const int m = m0 + wid * 32 + r * 16 + col;
          f32x4 v = acc2[s][r];
          #pragma unroll
          for (int p = 0; p < 2; ++p) {
            float a = v[2 * p] + bias[2 * p];
            float g = v[2 * p + 1] + bias[2 * p + 1];
            int op = s * 8 + q4 * 2 + p;
            if (op < half && m < MTOT) {
              int bbm = m / 2000;
              int t = m - bbm * 2000;
              int orr = op / 6, occ = op - orr * 6;
              out[(((size_t)bbm * 257 + boffk + orr) * TDIM + t) * 6 + occ] =
                  a * fast_sigmoid(g);
            }
          }
        }
      }
    }
  }
}

extern "C" void kernel_launch(void* const* d_in, const int* in_sizes, int n_in,
                              void* d_out, int out_size, void* d_ws, size_t ws_size,
                              hipStream_t stream) {
  const float* x      = (const float*)d_in[0];
  const float* norm_w = (const float*)d_in[1];
  const float* norm_b = (const float*)d_in[2];
  const float* fc1_w  = (const float*)d_in[3];
  const float* fc1_b  = (const float*)d_in[4];
  const float* fc2_w  = (const float*)d_in[5];
  const float* fc2_b  = (const float*)d_in[6];
  float* out = (float*)d_out;
  char* ws = (char*)d_ws;

  float* wsum  = (float*)(ws);
  float* wsq   = (float*)(ws + 512);
  float* gmean = (float*)(ws + 1024);
  float* grstd = (float*)(ws + 1536);
  size_t off = 4096;
  unsigned short* xtf = (unsigned short*)(ws + off); off += (size_t)NBANDS * NMTILE * 4 * 512 * 2;
  unsigned short* w1f = (unsigned short*)(ws + off); off += (size_t)NBANDS * 4 * 8 * 4 * 512 * 2;
  float* t1p = (float*)(ws + off); off += (size_t)NBANDS * HDIM * 4;
  float* t2p = (float*)(ws + off); off += (size_t)NBANDS * HDIM * 4;
  unsigned short* w2f = (unsigned short*)(ws + off); off += (size_t)NBANDS * 16 * 16 * 512 * 2;
  float* b2p = (float*)(ws + off); off += (size_t)NBANDS * OPAD * 4;

  // no hipMemsetAsync: k_prep_w1 block 0 zeroes wsum/wsq (R10: the 1KB fill
  // kernel cost ~73us per timed replay)
  hipLaunchKernelGGL(k_prep_w1, dim3(NBANDS * HDIM), dim3(128), 0, stream,
                     fc1_w, norm_w, norm_b, fc1_b, w1f, t1p, t2p, wsum, wsq);
  hipLaunchKernelGGL(k_prep_w2, dim3(NBANDS * 256), dim3(256), 0, stream,
                     fc2_w, fc2_b, w2f, b2p);
  hipLaunchKernelGGL(k_transpose, dim3(250, 4), dim3(256), 0, stream, x, xtf, wsum, wsq);
  hipLaunchKernelGGL(k_finalize, dim3(1), dim3(128), 0, stream, wsum, wsq, gmean, grstd);

  // dyn LDS: 4KB t12 + 2 x (8+SMAX)KB bufs; epilogue Ls = bw*128*6*4 reuses base
  hipFuncSetAttribute((const void*)k_gemm<13>, hipFuncAttributeMaxDynamicSharedMemorySize, 52224);
  hipFuncSetAttribute((const void*)k_gemm<6>,  hipFuncAttributeMaxDynamicSharedMemorySize, 32768);
  hipFuncSetAttribute((const void*)k_gemm<3>,  hipFuncAttributeMaxDynamicSharedMemorySize, 26624);
  hipLaunchKernelGGL((k_gemm<13>), dim3(8 * NMBK),  dim3(256), 52224, stream,
                     xtf, w1f, t1p, t2p, w2f, b2p, gmean, grstd, out, 23, 8 * NMBK);
  hipLaunchKernelGGL((k_gemm<6>),  dim3(12 * NMBK), dim3(256), 32768, stream,
                     xtf, w1f, t1p, t2p, w2f, b2p, gmean, grstd, out, 11, 12 * NMBK);
  hipLaunchKernelGGL((k_gemm<3>),  dim3(11 * NMBK), dim3(256), 26624, stream,
                     xtf, w1f, t1p, t2p, w2f, b2p, gmean, grstd, out, 0,  11 * NMBK);
}